// Round 1
// baseline (415.323 us; speedup 1.0000x reference)
//
#include <hip/hip_runtime.h>
#include <hip/hip_bf16.h>

#define NNODES 50000
#define NEDGES 800000
#define HID 256
#define BN_EPS 1e-5f
#define SCAN_B ((NNODES + 255) / 256)   // 196 blocks

typedef __attribute__((ext_vector_type(8))) short short8v;
typedef __attribute__((ext_vector_type(4))) float f32x4;
typedef __attribute__((ext_vector_type(2))) float f32x2;

__device__ inline void load_lds16(const void* g, void* l) {
    __builtin_amdgcn_global_load_lds(
        (const __attribute__((address_space(1))) unsigned int*)g,
        (__attribute__((address_space(3))) unsigned int*)l, 16, 0, 0);
}

// ---------------- CSR build ----------------
__global__ void k_countrank(const int* __restrict__ ei, int* __restrict__ cnt,
                            int* __restrict__ rank, int nE) {
    int e = blockIdx.x * blockDim.x + threadIdx.x;
    if (e < nE) rank[e] = atomicAdd(&cnt[ei[nE + e]], 1);
}

__global__ void k_bsum(const int* __restrict__ cnt, int* __restrict__ loc,
                       int* __restrict__ bsum, int n) {
    __shared__ int sh[256];
    int tid = threadIdx.x;
    int i = blockIdx.x * 256 + tid;
    int v = (i < n) ? cnt[i] : 0;
    sh[tid] = v;
    __syncthreads();
    for (int off = 1; off < 256; off <<= 1) {
        int t = (tid >= off) ? sh[tid - off] : 0;
        __syncthreads();
        sh[tid] += t;
        __syncthreads();
    }
    if (i < n) loc[i] = sh[tid] - v;
    if (tid == 255) bsum[blockIdx.x] = sh[255];
}

__global__ void k_bscan(int* __restrict__ bsum, int nb) {
    __shared__ int sh[256];
    int tid = threadIdx.x;
    int v = (tid < nb) ? bsum[tid] : 0;
    sh[tid] = v;
    __syncthreads();
    for (int off = 1; off < 256; off <<= 1) {
        int t = (tid >= off) ? sh[tid - off] : 0;
        __syncthreads();
        sh[tid] += t;
        __syncthreads();
    }
    if (tid < nb) bsum[tid] = sh[tid] - v;
}

__global__ void k_addoff(const int* __restrict__ loc, const int* __restrict__ bsum,
                         int* __restrict__ rowptr, int n, int nE) {
    int i = blockIdx.x * 256 + threadIdx.x;
    if (i < n) rowptr[i] = loc[i] + bsum[blockIdx.x];
    if (i == 0) rowptr[n] = nE;
}

__global__ void k_fill2(const int* __restrict__ ei, const int* __restrict__ rowptr,
                        const int* __restrict__ rank, int* __restrict__ col, int nE) {
    int e = blockIdx.x * blockDim.x + threadIdx.x;
    if (e < nE) col[rowptr[ei[nE + e]] + rank[e]] = ei[e];
}

// ---------------- fused prep: cast x->bf16+fp8, transpose weights, zero cnt
// ranges: [0,1600000) cast float4 ; [.., +327680) transpose ; [.., +50000) zero
#define PREP_CAST 1600000
#define PREP_TR   327680
__global__ void k_prep(const float* __restrict__ x,
                       __hip_bfloat16* __restrict__ xb, unsigned char* __restrict__ x8,
                       const float* __restrict__ s0, const float* __restrict__ s1,
                       const float* __restrict__ s2, const float* __restrict__ s3,
                       const float* __restrict__ s4, const float* __restrict__ s5,
                       __hip_bfloat16* __restrict__ d0, __hip_bfloat16* __restrict__ d1,
                       __hip_bfloat16* __restrict__ d2, __hip_bfloat16* __restrict__ d3,
                       __hip_bfloat16* __restrict__ d4, __hip_bfloat16* __restrict__ d5,
                       int* __restrict__ cnt) {
    int f = blockIdx.x * blockDim.x + threadIdx.x;
    if (f < PREP_CAST) {
        float4 v = *(const float4*)(x + f * 4);
        union { uint2 u; unsigned short s[4]; } ob;
        ob.s[0] = __bfloat16_as_ushort(__float2bfloat16(v.x));
        ob.s[1] = __bfloat16_as_ushort(__float2bfloat16(v.y));
        ob.s[2] = __bfloat16_as_ushort(__float2bfloat16(v.z));
        ob.s[3] = __bfloat16_as_ushort(__float2bfloat16(v.w));
        *(uint2*)(xb + f * 4) = ob.u;
        int p = __builtin_amdgcn_cvt_pk_fp8_f32(v.x, v.y, 0, false);
        p = __builtin_amdgcn_cvt_pk_fp8_f32(v.z, v.w, p, true);
        *(int*)(x8 + f * 4) = p;
    } else if (f < PREP_CAST + PREP_TR) {
        int r = f - PREP_CAST;
        const float* src; __hip_bfloat16* dst; int K; int i;
        if (r < 65536) {
            K = 128;
            if (r < 32768) { src = s0; dst = d0; i = r; }
            else           { src = s1; dst = d1; i = r - 32768; }
        } else {
            K = 256;
            int q = r - 65536;
            int wsel = q >> 16;
            i = q & 65535;
            src = (wsel == 0) ? s2 : (wsel == 1) ? s3 : (wsel == 2) ? s4 : s5;
            dst = (wsel == 0) ? d2 : (wsel == 1) ? d3 : (wsel == 2) ? d4 : d5;
        }
        int k = i >> 8;
        int nn = i & 255;
        dst[nn * K + k] = __float2bfloat16(src[i]);
    } else {
        int i = f - PREP_CAST - PREP_TR;
        if (i < NNODES) cnt[i] = 0;
    }
}

// ---------------- mean aggregation over fp8 table -> bf16 mean ----------
template <int D, int U>
__global__ void k_meanf8(const unsigned char* __restrict__ x8,
                         const int* __restrict__ rowptr, const int* __restrict__ col,
                         __hip_bfloat16* __restrict__ mean, int n) {
    constexpr int CPL = D / 16;
    constexpr int R = 64 / CPL;
    int gw = (blockIdx.x * blockDim.x + threadIdx.x) >> 6;
    int lane = threadIdx.x & 63;
    if (gw >= n) return;
    int beg = rowptr[gw], end = rowptr[gw + 1];
    int sub = lane / CPL;
    int fpos = lane % CPL;
    const uint4* base = (const uint4*)x8;   // CPL uint4 per row

    float acc[16];
#pragma unroll
    for (int j = 0; j < 16; j++) acc[j] = 0.f;

    for (int p0 = beg; p0 < end; p0 += U * R) {
        int idx[U]; bool ok[U];
#pragma unroll
        for (int u = 0; u < U; u++) {
            int p = p0 + u * R + sub;
            ok[u] = (p < end);
            idx[u] = ok[u] ? col[p] : 0;
        }
        uint4 v[U];
#pragma unroll
        for (int u = 0; u < U; u++) {
            uint4 t = {0u, 0u, 0u, 0u};
            if (ok[u]) t = base[(size_t)idx[u] * CPL + fpos];
            v[u] = t;
        }
#pragma unroll
        for (int u = 0; u < U; u++) {
            const unsigned int uu[4] = {v[u].x, v[u].y, v[u].z, v[u].w};
#pragma unroll
            for (int q = 0; q < 4; q++) {
                f32x2 lo = __builtin_amdgcn_cvt_pk_f32_fp8(uu[q], false);
                f32x2 hi = __builtin_amdgcn_cvt_pk_f32_fp8(uu[q], true);
                acc[4 * q + 0] += lo.x;
                acc[4 * q + 1] += lo.y;
                acc[4 * q + 2] += hi.x;
                acc[4 * q + 3] += hi.y;
            }
        }
    }

    if constexpr (R >= 8) {
#pragma unroll
        for (int j = 0; j < 16; j++) acc[j] += __shfl_xor(acc[j], 8, 64);
    }
#pragma unroll
    for (int j = 0; j < 16; j++) acc[j] += __shfl_xor(acc[j], 16, 64);
#pragma unroll
    for (int j = 0; j < 16; j++) acc[j] += __shfl_xor(acc[j], 32, 64);

    if (sub == 0) {
        float inv = (end > beg) ? 1.f / (float)(end - beg) : 0.f;
        union { uint4 v[2]; unsigned short s[16]; } o;
#pragma unroll
        for (int j = 0; j < 16; j++)
            o.s[j] = __bfloat16_as_ushort(__float2bfloat16(acc[j] * inv));
        uint4* dst = (uint4*)(mean + (size_t)gw * D + fpos * 16);
        dst[0] = o.v[0];
        dst[1] = o.v[1];
    }
}

// ---------------- streaming GEMM + BN (+ReLU) -------------------------------
// out[n,256] = act( (A1@W1 + A2@W2 + bl - rm) * scale + shift )
//
// Structure (replaces the barrier-per-K-step staged GEMM, which was
// latency-bound at MfmaUtil 7%):
//  - block = 256 rows x 64 cols, 4 waves (each wave 64x64). grid = 196*4.
//  - B (both weight slices, K_eff = 2*KH) staged to LDS ONCE, layout
//    [k8][col][8elem] so the wave's ds_read_b128 has consecutive lanes on
//    consecutive 16B -> conflict-free.
//  - A fragments loaded per-lane straight from global (row = ml, k = quad*8),
//    depth-2 register double-buffer, fully unrolled -> counted vmcnt, and
//    NO barriers in the main loop: waves run free, ILP hides LLC latency.
//  - epilogue: one barrier, reuse dead B-LDS as per-wave f32 scratch, then
//    write contiguous 128B (bf16) / 256B (f32) / 64B (fp8) row segments.
template <int KH, typename OutT, int RELU, int W8>
__launch_bounds__(256, 2)
__global__ void k_gemm3(const __hip_bfloat16* __restrict__ A1,
                        const __hip_bfloat16* __restrict__ A2,
                        const __hip_bfloat16* __restrict__ W1t,
                        const __hip_bfloat16* __restrict__ W2t,
                        const float* __restrict__ bl,
                        const float* __restrict__ g,
                        const float* __restrict__ bb,
                        const float* __restrict__ rm,
                        const float* __restrict__ rv,
                        OutT* __restrict__ out, unsigned char* __restrict__ out8,
                        int n) {
    constexpr int NSTEP = KH / 16;       // k-steps of 32 across both matrices
    constexpr int K8TOT = KH / 4;        // 16B chunks per col across both matrices
    __shared__ uint4 ldsv[4096];         // 64 KB: B panel, then epilogue scratch
    char* lds = (char*)ldsv;
    int tid = threadIdx.x;
    int rb = blockIdx.x >> 2, ct = blockIdx.x & 3;
    int colbase = ct * 64;

    // ---- stage B once: chunk j = k8*64 + c  ->  LDS[j*16] = Wt[col][k8*8..+8]
#pragma unroll
    for (int it = 0; it < K8TOT / 4; it++) {
        int j = tid + it * 256;
        int k8 = j >> 6, c = j & 63;
        const __hip_bfloat16* src =
            (k8 < KH / 8) ? (W1t + (size_t)(colbase + c) * KH + k8 * 8)
                          : (W2t + (size_t)(colbase + c) * KH + (k8 - KH / 8) * 8);
        *(uint4*)(lds + (size_t)j * 16) = *(const uint4*)src;
    }

    int lane = tid & 63, wv = tid >> 6;
    int quad = lane >> 4, ml = lane & 15;
    int row0 = rb * 256 + wv * 64;

    // per-lane A fragment base pointers (row = ml within each 16-row group)
    const short8v* p1[4];
    const short8v* p2[4];
#pragma unroll
    for (int i = 0; i < 4; i++) {
        int r = row0 + i * 16 + ml;
        if (r > n - 1) r = n - 1;
        p1[i] = (const short8v*)(A1 + (size_t)r * KH) + quad;
        p2[i] = (const short8v*)(A2 + (size_t)r * KH) + quad;
    }

    f32x4 acc[4][4];
#pragma unroll
    for (int i = 0; i < 4; i++)
#pragma unroll
        for (int t = 0; t < 4; t++) acc[i][t] = {0.f, 0.f, 0.f, 0.f};

    short8v ab[3][4];
    // prefetch steps 0,1 (pure register loads; fine to be in flight at barrier)
#pragma unroll
    for (int s = 0; s < 2; s++) {
        const short8v* const* pp = (s < NSTEP / 2) ? p1 : p2;
        int sh = (s < NSTEP / 2) ? s : s - NSTEP / 2;
#pragma unroll
        for (int i = 0; i < 4; i++) ab[s][i] = pp[i][sh * 4];
    }
    __syncthreads();

#pragma unroll
    for (int s = 0; s < NSTEP; s++) {
        int sn = s + 2;
        if (sn < NSTEP) {
            const short8v* const* pp = (sn < NSTEP / 2) ? p1 : p2;
            int sh = (sn < NSTEP / 2) ? sn : sn - NSTEP / 2;
#pragma unroll
            for (int i = 0; i < 4; i++) ab[sn % 3][i] = pp[i][sh * 4];
        }
        short8v bfr[4];
#pragma unroll
        for (int t = 0; t < 4; t++)
            bfr[t] = *(const short8v*)(lds + ((size_t)((s * 4 + quad) * 64 + t * 16 + ml)) * 16);
#pragma unroll
        for (int t = 0; t < 4; t++)
#pragma unroll
            for (int i = 0; i < 4; i++)
                acc[i][t] = __builtin_amdgcn_mfma_f32_16x16x32_bf16(
                    ab[s % 3][i], bfr[t], acc[i][t], 0, 0, 0);
    }

    // ---- epilogue: BN -> per-wave LDS transpose -> wide coalesced stores ----
    __syncthreads();                        // all waves done reading B panel
    float* scr = (float*)(lds + wv * 16384);  // 64x64 f32 per wave
#pragma unroll
    for (int t = 0; t < 4; t++) {
        int c = colbase + t * 16 + ml;
        float sv = g[c] * rsqrtf(rv[c] + BN_EPS);
        float tv = (bl[c] - rm[c]) * sv + bb[c];
#pragma unroll
        for (int i = 0; i < 4; i++)
#pragma unroll
            for (int r = 0; r < 4; r++) {
                float v = acc[i][t][r] * sv + tv;
                if (RELU) v = fmaxf(v, 0.f);
                scr[(i * 16 + quad * 4 + r) * 64 + t * 16 + ml] = v;
            }
    }
    // same-wave ds_write -> ds_read: compiler inserts the lgkmcnt wait
    int rl8 = lane >> 3, c8 = (lane & 7) * 8;
#pragma unroll
    for (int p = 0; p < 8; p++) {
        int rowl = p * 8 + rl8;
        int row = row0 + rowl;
        f32x4 v0 = *(const f32x4*)(scr + rowl * 64 + c8);
        f32x4 v1 = *(const f32x4*)(scr + rowl * 64 + c8 + 4);
        if (row < n) {
            if constexpr (sizeof(OutT) == 2) {
                union { uint4 u; unsigned short s[8]; } o;
                o.s[0] = __bfloat16_as_ushort(__float2bfloat16(v0.x));
                o.s[1] = __bfloat16_as_ushort(__float2bfloat16(v0.y));
                o.s[2] = __bfloat16_as_ushort(__float2bfloat16(v0.z));
                o.s[3] = __bfloat16_as_ushort(__float2bfloat16(v0.w));
                o.s[4] = __bfloat16_as_ushort(__float2bfloat16(v1.x));
                o.s[5] = __bfloat16_as_ushort(__float2bfloat16(v1.y));
                o.s[6] = __bfloat16_as_ushort(__float2bfloat16(v1.z));
                o.s[7] = __bfloat16_as_ushort(__float2bfloat16(v1.w));
                *(uint4*)(out + (size_t)row * HID + colbase + c8) = o.u;
            } else {
                float* dst = (float*)out + (size_t)row * HID + colbase + c8;
                *(f32x4*)dst = v0;
                *(f32x4*)(dst + 4) = v1;
            }
            if constexpr (W8) {
                int lo = __builtin_amdgcn_cvt_pk_fp8_f32(v0.x, v0.y, 0, false);
                lo = __builtin_amdgcn_cvt_pk_fp8_f32(v0.z, v0.w, lo, true);
                int hi = __builtin_amdgcn_cvt_pk_fp8_f32(v1.x, v1.y, 0, false);
                hi = __builtin_amdgcn_cvt_pk_fp8_f32(v1.z, v1.w, hi, true);
                uint2 u2 = {(unsigned)lo, (unsigned)hi};
                *(uint2*)(out8 + (size_t)row * HID + colbase + c8) = u2;
            }
        }
    }
}

extern "C" void kernel_launch(void* const* d_in, const int* in_sizes, int n_in,
                              void* d_out, int out_size, void* d_ws, size_t ws_size,
                              hipStream_t stream) {
    const float* x = (const float*)d_in[0];
    const int* ei = (const int*)d_in[1];
    const float *Wl[3], *blv[3], *Wr[3], *g[3], *bb[3], *rm[3], *rv[3];
    for (int i = 0; i < 3; i++) {
        int b = 2 + i * 7;
        Wl[i]  = (const float*)d_in[b + 0];
        blv[i] = (const float*)d_in[b + 1];
        Wr[i]  = (const float*)d_in[b + 2];
        g[i]   = (const float*)d_in[b + 3];
        bb[i]  = (const float*)d_in[b + 4];
        rm[i]  = (const float*)d_in[b + 5];
        rv[i]  = (const float*)d_in[b + 6];
    }

    // scratch inside d_out (fully overwritten by the final GEMM):
    char* ob = (char*)d_out;
    __hip_bfloat16* xb = (__hip_bfloat16*)ob;                              // 12.8 MB
    __hip_bfloat16* h0 = (__hip_bfloat16*)(ob + (size_t)NNODES * 128 * 2); // 25.6 MB

    char* w = (char*)d_ws;
    size_t off = 0;
    auto alloc = [&](size_t bytes) {
        void* p = w + off;
        off += (bytes + 255) & ~(size_t)255;
        return p;
    };
    int* rowptr = (int*)alloc((NNODES + 1) * sizeof(int));
    int* cnt    = (int*)alloc(NNODES * sizeof(int));
    int* loc    = (int*)alloc(NNODES * sizeof(int));
    int* bsum   = (int*)alloc(SCAN_B * sizeof(int));
    int* rank   = (int*)alloc(NEDGES * sizeof(int));
    int* col    = (int*)alloc(NEDGES * sizeof(int));
    __hip_bfloat16* meanb = (__hip_bfloat16*)alloc((size_t)NNODES * HID * 2);
    __hip_bfloat16* h1    = (__hip_bfloat16*)alloc((size_t)NNODES * HID * 2);
    unsigned char* x8   = (unsigned char*)alloc((size_t)NNODES * 128);
    unsigned char* h0f8 = (unsigned char*)alloc((size_t)NNODES * HID);
    unsigned char* h1f8 = (unsigned char*)alloc((size_t)NNODES * HID);
    __hip_bfloat16* Wt[6];
    int Ks[6] = {128, 128, 256, 256, 256, 256};
    for (int i = 0; i < 6; i++) Wt[i] = (__hip_bfloat16*)alloc((size_t)Ks[i] * HID * 2);

    // fused prep: cast x (bf16 + fp8), transpose weights, zero cnt
    int prepTotal = PREP_CAST + PREP_TR + NNODES;
    k_prep<<<(prepTotal + 255) / 256, 256, 0, stream>>>(
        x, xb, x8, Wl[0], Wr[0], Wl[1], Wr[1], Wl[2], Wr[2],
        Wt[0], Wt[1], Wt[2], Wt[3], Wt[4], Wt[5], cnt);

    // CSR build
    k_countrank<<<(NEDGES + 255) / 256, 256, 0, stream>>>(ei, cnt, rank, NEDGES);
    k_bsum<<<SCAN_B, 256, 0, stream>>>(cnt, loc, bsum, NNODES);
    k_bscan<<<1, 256, 0, stream>>>(bsum, SCAN_B);
    k_addoff<<<SCAN_B, 256, 0, stream>>>(loc, bsum, rowptr, NNODES, NEDGES);
    k_fill2<<<(NEDGES + 255) / 256, 256, 0, stream>>>(ei, rowptr, rank, col, NEDGES);

    int meanBlocks = (NNODES * 64 + 255) / 256;      // one wave per node
    int gemmBlocks = ((NNODES + 255) / 256) * 4;     // 196 row-tiles x 4 col-tiles

    // layer 0 (KH=128): fp8 gather (CPL=8, R=8, U=2 -> 16 in flight)
    k_meanf8<128, 2><<<meanBlocks, 256, 0, stream>>>(x8, rowptr, col, meanb, NNODES);
    k_gemm3<128, __hip_bfloat16, 1, 1><<<gemmBlocks, 256, 0, stream>>>(meanb, xb, Wt[0], Wt[1],
        blv[0], g[0], bb[0], rm[0], rv[0], h0, h0f8, NNODES);

    // layer 1 (KH=256): fp8 gather (CPL=16, R=4, U=4 -> 16 in flight)
    k_meanf8<256, 4><<<meanBlocks, 256, 0, stream>>>(h0f8, rowptr, col, meanb, NNODES);
    k_gemm3<256, __hip_bfloat16, 1, 1><<<gemmBlocks, 256, 0, stream>>>(meanb, h0, Wt[2], Wt[3],
        blv[1], g[1], bb[1], rm[1], rv[1], h1, h1f8, NNODES);

    // layer 2 (KH=256, no relu) -> f32 d_out
    k_meanf8<256, 4><<<meanBlocks, 256, 0, stream>>>(h1f8, rowptr, col, meanb, NNODES);
    k_gemm3<256, float, 0, 0><<<gemmBlocks, 256, 0, stream>>>(meanb, h1, Wt[4], Wt[5],
        blv[2], g[2], bb[2], rm[2], rv[2], (float*)d_out, (unsigned char*)nullptr, NNODES);
}

// Round 2
// 397.414 us; speedup vs baseline: 1.0451x; 1.0451x over previous
//
#include <hip/hip_runtime.h>
#include <hip/hip_bf16.h>

#define NNODES 50000
#define NEDGES 800000
#define HID 256
#define BN_EPS 1e-5f
#define SCAN_B ((NNODES + 255) / 256)   // 196 blocks

typedef __attribute__((ext_vector_type(8))) short short8v;
typedef __attribute__((ext_vector_type(4))) float f32x4;
typedef __attribute__((ext_vector_type(2))) float f32x2;

__device__ inline void load_lds16(const void* g, void* l) {
    __builtin_amdgcn_global_load_lds(
        (const __attribute__((address_space(1))) unsigned int*)g,
        (__attribute__((address_space(3))) unsigned int*)l, 16, 0, 0);
}

// ---------------- CSR build ----------------
__global__ void k_countrank(const int* __restrict__ ei, int* __restrict__ cnt,
                            int* __restrict__ rank, int nE) {
    int e = blockIdx.x * blockDim.x + threadIdx.x;
    if (e < nE) rank[e] = atomicAdd(&cnt[ei[nE + e]], 1);
}

__global__ void k_bsum(const int* __restrict__ cnt, int* __restrict__ loc,
                       int* __restrict__ bsum, int n) {
    __shared__ int sh[256];
    int tid = threadIdx.x;
    int i = blockIdx.x * 256 + tid;
    int v = (i < n) ? cnt[i] : 0;
    sh[tid] = v;
    __syncthreads();
    for (int off = 1; off < 256; off <<= 1) {
        int t = (tid >= off) ? sh[tid - off] : 0;
        __syncthreads();
        sh[tid] += t;
        __syncthreads();
    }
    if (i < n) loc[i] = sh[tid] - v;
    if (tid == 255) bsum[blockIdx.x] = sh[255];
}

__global__ void k_bscan(int* __restrict__ bsum, int nb) {
    __shared__ int sh[256];
    int tid = threadIdx.x;
    int v = (tid < nb) ? bsum[tid] : 0;
    sh[tid] = v;
    __syncthreads();
    for (int off = 1; off < 256; off <<= 1) {
        int t = (tid >= off) ? sh[tid - off] : 0;
        __syncthreads();
        sh[tid] += t;
        __syncthreads();
    }
    if (tid < nb) bsum[tid] = sh[tid] - v;
}

__global__ void k_addoff(const int* __restrict__ loc, const int* __restrict__ bsum,
                         int* __restrict__ rowptr, int n, int nE) {
    int i = blockIdx.x * 256 + threadIdx.x;
    if (i < n) rowptr[i] = loc[i] + bsum[blockIdx.x];
    if (i == 0) rowptr[n] = nE;
}

__global__ void k_fill2(const int* __restrict__ ei, const int* __restrict__ rowptr,
                        const int* __restrict__ rank, int* __restrict__ col, int nE) {
    int e = blockIdx.x * blockDim.x + threadIdx.x;
    if (e < nE) col[rowptr[ei[nE + e]] + rank[e]] = ei[e];
}

// ---------------- fused prep: cast x->bf16+fp8, transpose weights, zero cnt
// ranges: [0,1600000) cast float4 ; [.., +327680) transpose ; [.., +50000) zero
#define PREP_CAST 1600000
#define PREP_TR   327680
__global__ void k_prep(const float* __restrict__ x,
                       __hip_bfloat16* __restrict__ xb, unsigned char* __restrict__ x8,
                       const float* __restrict__ s0, const float* __restrict__ s1,
                       const float* __restrict__ s2, const float* __restrict__ s3,
                       const float* __restrict__ s4, const float* __restrict__ s5,
                       __hip_bfloat16* __restrict__ d0, __hip_bfloat16* __restrict__ d1,
                       __hip_bfloat16* __restrict__ d2, __hip_bfloat16* __restrict__ d3,
                       __hip_bfloat16* __restrict__ d4, __hip_bfloat16* __restrict__ d5,
                       int* __restrict__ cnt) {
    int f = blockIdx.x * blockDim.x + threadIdx.x;
    if (f < PREP_CAST) {
        float4 v = *(const float4*)(x + f * 4);
        union { uint2 u; unsigned short s[4]; } ob;
        ob.s[0] = __bfloat16_as_ushort(__float2bfloat16(v.x));
        ob.s[1] = __bfloat16_as_ushort(__float2bfloat16(v.y));
        ob.s[2] = __bfloat16_as_ushort(__float2bfloat16(v.z));
        ob.s[3] = __bfloat16_as_ushort(__float2bfloat16(v.w));
        *(uint2*)(xb + f * 4) = ob.u;
        int p = __builtin_amdgcn_cvt_pk_fp8_f32(v.x, v.y, 0, false);
        p = __builtin_amdgcn_cvt_pk_fp8_f32(v.z, v.w, p, true);
        *(int*)(x8 + f * 4) = p;
    } else if (f < PREP_CAST + PREP_TR) {
        int r = f - PREP_CAST;
        const float* src; __hip_bfloat16* dst; int K; int i;
        if (r < 65536) {
            K = 128;
            if (r < 32768) { src = s0; dst = d0; i = r; }
            else           { src = s1; dst = d1; i = r - 32768; }
        } else {
            K = 256;
            int q = r - 65536;
            int wsel = q >> 16;
            i = q & 65535;
            src = (wsel == 0) ? s2 : (wsel == 1) ? s3 : (wsel == 2) ? s4 : s5;
            dst = (wsel == 0) ? d2 : (wsel == 1) ? d3 : (wsel == 2) ? d4 : d5;
        }
        int k = i >> 8;
        int nn = i & 255;
        dst[nn * K + k] = __float2bfloat16(src[i]);
    } else {
        int i = f - PREP_CAST - PREP_TR;
        if (i < NNODES) cnt[i] = 0;
    }
}

// ---------------- mean aggregation over fp8 table -> bf16 mean ----------
template <int D, int U>
__global__ void k_meanf8(const unsigned char* __restrict__ x8,
                         const int* __restrict__ rowptr, const int* __restrict__ col,
                         __hip_bfloat16* __restrict__ mean, int n) {
    constexpr int CPL = D / 16;
    constexpr int R = 64 / CPL;
    int gw = (blockIdx.x * blockDim.x + threadIdx.x) >> 6;
    int lane = threadIdx.x & 63;
    if (gw >= n) return;
    int beg = rowptr[gw], end = rowptr[gw + 1];
    int sub = lane / CPL;
    int fpos = lane % CPL;
    const uint4* base = (const uint4*)x8;   // CPL uint4 per row

    float acc[16];
#pragma unroll
    for (int j = 0; j < 16; j++) acc[j] = 0.f;

    for (int p0 = beg; p0 < end; p0 += U * R) {
        int idx[U]; bool ok[U];
#pragma unroll
        for (int u = 0; u < U; u++) {
            int p = p0 + u * R + sub;
            ok[u] = (p < end);
            idx[u] = ok[u] ? col[p] : 0;
        }
        uint4 v[U];
#pragma unroll
        for (int u = 0; u < U; u++) {
            uint4 t = {0u, 0u, 0u, 0u};
            if (ok[u]) t = base[(size_t)idx[u] * CPL + fpos];
            v[u] = t;
        }
#pragma unroll
        for (int u = 0; u < U; u++) {
            const unsigned int uu[4] = {v[u].x, v[u].y, v[u].z, v[u].w};
#pragma unroll
            for (int q = 0; q < 4; q++) {
                f32x2 lo = __builtin_amdgcn_cvt_pk_f32_fp8(uu[q], false);
                f32x2 hi = __builtin_amdgcn_cvt_pk_f32_fp8(uu[q], true);
                acc[4 * q + 0] += lo.x;
                acc[4 * q + 1] += lo.y;
                acc[4 * q + 2] += hi.x;
                acc[4 * q + 3] += hi.y;
            }
        }
    }

    if constexpr (R >= 8) {
#pragma unroll
        for (int j = 0; j < 16; j++) acc[j] += __shfl_xor(acc[j], 8, 64);
    }
#pragma unroll
    for (int j = 0; j < 16; j++) acc[j] += __shfl_xor(acc[j], 16, 64);
#pragma unroll
    for (int j = 0; j < 16; j++) acc[j] += __shfl_xor(acc[j], 32, 64);

    if (sub == 0) {
        float inv = (end > beg) ? 1.f / (float)(end - beg) : 0.f;
        union { uint4 v[2]; unsigned short s[16]; } o;
#pragma unroll
        for (int j = 0; j < 16; j++)
            o.s[j] = __bfloat16_as_ushort(__float2bfloat16(acc[j] * inv));
        uint4* dst = (uint4*)(mean + (size_t)gw * D + fpos * 16);
        dst[0] = o.v[0];
        dst[1] = o.v[1];
    }
}

// ---------------- streaming GEMM + BN (+ReLU) -------------------------------
// out[n,256] = act( (A1@W1 + A2@W2 + bl - rm) * scale + shift )
//
// vs previous round (55.6us, FETCH=100MB = 2x A over-fetch, HBM 35%):
//  - XCD-grouped swizzle: hw block i -> logical l=(i&7)*(grid/8)+(i>>3);
//    rb=l>>2, ct=l&3. All 4 col-tiles of a row-tile now run on the SAME XCD
//    nearly simultaneously -> A row-panel fetched from HBM once, 3x L2 hits.
//    (784 % 8 == 0 -> bijective.)
//  - A prefetch depth 3 with 4 rotating fragment buffers (12 loads in
//    flight/lane) -> covers ~480cy of HBM latency vs ~160cy at depth 2.
//  - B panel staged via global_load_lds (per-lane global src, linear LDS
//    dest), no VGPR round-trip in the prologue.
//  - still ZERO barriers in the main loop; epilogue unchanged (LDS
//    transpose -> wide coalesced stores).
template <int KH, typename OutT, int RELU, int W8>
__launch_bounds__(256, 2)
__global__ void k_gemm3(const __hip_bfloat16* __restrict__ A1,
                        const __hip_bfloat16* __restrict__ A2,
                        const __hip_bfloat16* __restrict__ W1t,
                        const __hip_bfloat16* __restrict__ W2t,
                        const float* __restrict__ bl,
                        const float* __restrict__ g,
                        const float* __restrict__ bb,
                        const float* __restrict__ rm,
                        const float* __restrict__ rv,
                        OutT* __restrict__ out, unsigned char* __restrict__ out8,
                        int n) {
    constexpr int NSTEP = KH / 16;       // k-steps of 32 across both matrices
    constexpr int K8TOT = KH / 4;        // 16B chunks per col across both matrices
    __shared__ uint4 ldsv[4096];         // 64 KB: B panel, then epilogue scratch
    char* lds = (char*)ldsv;
    int tid = threadIdx.x;
    // XCD-grouped tile mapping (dispatch round-robins XCD = blockIdx % 8)
    int l = (blockIdx.x & 7) * (gridDim.x >> 3) + (blockIdx.x >> 3);
    int rb = l >> 2, ct = l & 3;
    int colbase = ct * 64;

    // ---- stage B once via global_load_lds: chunk j = k8*64 + c
#pragma unroll
    for (int it = 0; it < K8TOT / 4; it++) {
        int j = tid + it * 256;
        int k8 = j >> 6, c = j & 63;
        const __hip_bfloat16* src =
            (k8 < KH / 8) ? (W1t + (size_t)(colbase + c) * KH + k8 * 8)
                          : (W2t + (size_t)(colbase + c) * KH + (k8 - KH / 8) * 8);
        load_lds16(src, lds + (size_t)j * 16);
    }

    int lane = tid & 63, wv = tid >> 6;
    int quad = lane >> 4, ml = lane & 15;
    int row0 = rb * 256 + wv * 64;

    // per-lane A fragment base pointers (row = ml within each 16-row group)
    const short8v* p1[4];
    const short8v* p2[4];
#pragma unroll
    for (int i = 0; i < 4; i++) {
        int r = row0 + i * 16 + ml;
        if (r > n - 1) r = n - 1;
        p1[i] = (const short8v*)(A1 + (size_t)r * KH) + quad;
        p2[i] = (const short8v*)(A2 + (size_t)r * KH) + quad;
    }

    f32x4 acc[4][4];
#pragma unroll
    for (int i = 0; i < 4; i++)
#pragma unroll
        for (int t = 0; t < 4; t++) acc[i][t] = {0.f, 0.f, 0.f, 0.f};

    short8v ab[4][4];
    // prefetch steps 0..2 (pure register loads; in flight across the barrier)
#pragma unroll
    for (int s = 0; s < 3; s++) {
        const short8v* const* pp = (s < NSTEP / 2) ? p1 : p2;
        int sh = (s < NSTEP / 2) ? s : s - NSTEP / 2;
#pragma unroll
        for (int i = 0; i < 4; i++) ab[s][i] = pp[i][sh * 4];
    }
    __syncthreads();   // B panel resident (compiler drains vmcnt before barrier)

#pragma unroll
    for (int s = 0; s < NSTEP; s++) {
        int sn = s + 3;
        if (sn < NSTEP) {
            const short8v* const* pp = (sn < NSTEP / 2) ? p1 : p2;
            int sh = (sn < NSTEP / 2) ? sn : sn - NSTEP / 2;
#pragma unroll
            for (int i = 0; i < 4; i++) ab[sn & 3][i] = pp[i][sh * 4];
        }
        short8v bfr[4];
#pragma unroll
        for (int t = 0; t < 4; t++)
            bfr[t] = *(const short8v*)(lds + ((size_t)((s * 4 + quad) * 64 + t * 16 + ml)) * 16);
#pragma unroll
        for (int t = 0; t < 4; t++)
#pragma unroll
            for (int i = 0; i < 4; i++)
                acc[i][t] = __builtin_amdgcn_mfma_f32_16x16x32_bf16(
                    ab[s & 3][i], bfr[t], acc[i][t], 0, 0, 0);
    }

    // ---- epilogue: BN -> per-wave LDS transpose -> wide coalesced stores ----
    __syncthreads();                        // all waves done reading B panel
    float* scr = (float*)(lds + wv * 16384);  // 64x64 f32 per wave
#pragma unroll
    for (int t = 0; t < 4; t++) {
        int c = colbase + t * 16 + ml;
        float sv = g[c] * rsqrtf(rv[c] + BN_EPS);
        float tv = (bl[c] - rm[c]) * sv + bb[c];
#pragma unroll
        for (int i = 0; i < 4; i++)
#pragma unroll
            for (int r = 0; r < 4; r++) {
                float v = acc[i][t][r] * sv + tv;
                if (RELU) v = fmaxf(v, 0.f);
                scr[(i * 16 + quad * 4 + r) * 64 + t * 16 + ml] = v;
            }
    }
    // same-wave ds_write -> ds_read: compiler inserts the lgkmcnt wait
    int rl8 = lane >> 3, c8 = (lane & 7) * 8;
#pragma unroll
    for (int p = 0; p < 8; p++) {
        int rowl = p * 8 + rl8;
        int row = row0 + rowl;
        f32x4 v0 = *(const f32x4*)(scr + rowl * 64 + c8);
        f32x4 v1 = *(const f32x4*)(scr + rowl * 64 + c8 + 4);
        if (row < n) {
            if constexpr (sizeof(OutT) == 2) {
                union { uint4 u; unsigned short s[8]; } o;
                o.s[0] = __bfloat16_as_ushort(__float2bfloat16(v0.x));
                o.s[1] = __bfloat16_as_ushort(__float2bfloat16(v0.y));
                o.s[2] = __bfloat16_as_ushort(__float2bfloat16(v0.z));
                o.s[3] = __bfloat16_as_ushort(__float2bfloat16(v0.w));
                o.s[4] = __bfloat16_as_ushort(__float2bfloat16(v1.x));
                o.s[5] = __bfloat16_as_ushort(__float2bfloat16(v1.y));
                o.s[6] = __bfloat16_as_ushort(__float2bfloat16(v1.z));
                o.s[7] = __bfloat16_as_ushort(__float2bfloat16(v1.w));
                *(uint4*)(out + (size_t)row * HID + colbase + c8) = o.u;
            } else {
                float* dst = (float*)out + (size_t)row * HID + colbase + c8;
                *(f32x4*)dst = v0;
                *(f32x4*)(dst + 4) = v1;
            }
            if constexpr (W8) {
                int lo = __builtin_amdgcn_cvt_pk_fp8_f32(v0.x, v0.y, 0, false);
                lo = __builtin_amdgcn_cvt_pk_fp8_f32(v0.z, v0.w, lo, true);
                int hi = __builtin_amdgcn_cvt_pk_fp8_f32(v1.x, v1.y, 0, false);
                hi = __builtin_amdgcn_cvt_pk_fp8_f32(v1.z, v1.w, hi, true);
                uint2 u2 = {(unsigned)lo, (unsigned)hi};
                *(uint2*)(out8 + (size_t)row * HID + colbase + c8) = u2;
            }
        }
    }
}

extern "C" void kernel_launch(void* const* d_in, const int* in_sizes, int n_in,
                              void* d_out, int out_size, void* d_ws, size_t ws_size,
                              hipStream_t stream) {
    const float* x = (const float*)d_in[0];
    const int* ei = (const int*)d_in[1];
    const float *Wl[3], *blv[3], *Wr[3], *g[3], *bb[3], *rm[3], *rv[3];
    for (int i = 0; i < 3; i++) {
        int b = 2 + i * 7;
        Wl[i]  = (const float*)d_in[b + 0];
        blv[i] = (const float*)d_in[b + 1];
        Wr[i]  = (const float*)d_in[b + 2];
        g[i]   = (const float*)d_in[b + 3];
        bb[i]  = (const float*)d_in[b + 4];
        rm[i]  = (const float*)d_in[b + 5];
        rv[i]  = (const float*)d_in[b + 6];
    }

    // scratch inside d_out (fully overwritten by the final GEMM):
    char* ob = (char*)d_out;
    __hip_bfloat16* xb = (__hip_bfloat16*)ob;                              // 12.8 MB
    __hip_bfloat16* h0 = (__hip_bfloat16*)(ob + (size_t)NNODES * 128 * 2); // 25.6 MB

    char* w = (char*)d_ws;
    size_t off = 0;
    auto alloc = [&](size_t bytes) {
        void* p = w + off;
        off += (bytes + 255) & ~(size_t)255;
        return p;
    };
    int* rowptr = (int*)alloc((NNODES + 1) * sizeof(int));
    int* cnt    = (int*)alloc(NNODES * sizeof(int));
    int* loc    = (int*)alloc(NNODES * sizeof(int));
    int* bsum   = (int*)alloc(SCAN_B * sizeof(int));
    int* rank   = (int*)alloc(NEDGES * sizeof(int));
    int* col    = (int*)alloc(NEDGES * sizeof(int));
    __hip_bfloat16* meanb = (__hip_bfloat16*)alloc((size_t)NNODES * HID * 2);
    __hip_bfloat16* h1    = (__hip_bfloat16*)alloc((size_t)NNODES * HID * 2);
    unsigned char* x8   = (unsigned char*)alloc((size_t)NNODES * 128);
    unsigned char* h0f8 = (unsigned char*)alloc((size_t)NNODES * HID);
    unsigned char* h1f8 = (unsigned char*)alloc((size_t)NNODES * HID);
    __hip_bfloat16* Wt[6];
    int Ks[6] = {128, 128, 256, 256, 256, 256};
    for (int i = 0; i < 6; i++) Wt[i] = (__hip_bfloat16*)alloc((size_t)Ks[i] * HID * 2);

    // fused prep: cast x (bf16 + fp8), transpose weights, zero cnt
    int prepTotal = PREP_CAST + PREP_TR + NNODES;
    k_prep<<<(prepTotal + 255) / 256, 256, 0, stream>>>(
        x, xb, x8, Wl[0], Wr[0], Wl[1], Wr[1], Wl[2], Wr[2],
        Wt[0], Wt[1], Wt[2], Wt[3], Wt[4], Wt[5], cnt);

    // CSR build
    k_countrank<<<(NEDGES + 255) / 256, 256, 0, stream>>>(ei, cnt, rank, NEDGES);
    k_bsum<<<SCAN_B, 256, 0, stream>>>(cnt, loc, bsum, NNODES);
    k_bscan<<<1, 256, 0, stream>>>(bsum, SCAN_B);
    k_addoff<<<SCAN_B, 256, 0, stream>>>(loc, bsum, rowptr, NNODES, NEDGES);
    k_fill2<<<(NEDGES + 255) / 256, 256, 0, stream>>>(ei, rowptr, rank, col, NEDGES);

    int meanBlocks = (NNODES * 64 + 255) / 256;      // one wave per node
    int gemmBlocks = ((NNODES + 255) / 256) * 4;     // 196 row-tiles x 4 col-tiles

    // layer 0 (KH=128): fp8 gather (CPL=8, R=8, U=2 -> 16 in flight)
    k_meanf8<128, 2><<<meanBlocks, 256, 0, stream>>>(x8, rowptr, col, meanb, NNODES);
    k_gemm3<128, __hip_bfloat16, 1, 1><<<gemmBlocks, 256, 0, stream>>>(meanb, xb, Wt[0], Wt[1],
        blv[0], g[0], bb[0], rm[0], rv[0], h0, h0f8, NNODES);

    // layer 1 (KH=256): fp8 gather (CPL=16, R=4, U=4 -> 16 in flight)
    k_meanf8<256, 4><<<meanBlocks, 256, 0, stream>>>(h0f8, rowptr, col, meanb, NNODES);
    k_gemm3<256, __hip_bfloat16, 1, 1><<<gemmBlocks, 256, 0, stream>>>(meanb, h0, Wt[2], Wt[3],
        blv[1], g[1], bb[1], rm[1], rv[1], h1, h1f8, NNODES);

    // layer 2 (KH=256, no relu) -> f32 d_out
    k_meanf8<256, 4><<<meanBlocks, 256, 0, stream>>>(h1f8, rowptr, col, meanb, NNODES);
    k_gemm3<256, float, 0, 0><<<gemmBlocks, 256, 0, stream>>>(meanb, h1, Wt[4], Wt[5],
        blv[2], g[2], bb[2], rm[2], rv[2], (float*)d_out, (unsigned char*)nullptr, NNODES);
}